// Round 8
// baseline (174.818 us; speedup 1.0000x reference)
//
#include <hip/hip_runtime.h>

typedef __bf16 bf16_t;
typedef __bf16 bf16x8 __attribute__((ext_vector_type(8)));
typedef _Float16 f16x4 __attribute__((ext_vector_type(4)));
typedef _Float16 f16x8 __attribute__((ext_vector_type(8)));
typedef float f32x4 __attribute__((ext_vector_type(4)));

// async global->LDS, 16B per lane. LDS dest must be wave-uniform base + lane*16.
__device__ __forceinline__ void gl_lds16(const void* g, void* l) {
  __builtin_amdgcn_global_load_lds(
      (const __attribute__((address_space(1))) unsigned int*)g,
      (__attribute__((address_space(3))) unsigned int*)l, 16, 0, 0);
}

// ---------------------------------------------------------------- fused prep kernel
// [0,2048): cast hs->bf16 ; [2048,4096): cast tk->bf16  (8 elems/thread, 16B stores)
// [4096,5632): transpose Wc ; [5632,6144): transpose Wp ; [6144,8192): tv^T -> fp16 (key-permuted)
__global__ __launch_bounds__(256) void prep_kernel(
    const float* __restrict__ hs, const float* __restrict__ tk, const float* __restrict__ tv,
    const float* __restrict__ Wc, const float* __restrict__ Wp,
    bf16_t* __restrict__ Ahs, bf16_t* __restrict__ Ktb, _Float16* __restrict__ Vtb,
    bf16_t* __restrict__ WcT, bf16_t* __restrict__ WpT) {
  const int blk = blockIdx.x;
  const int tid = threadIdx.x;
  if (blk < 4096) {
    const float4* src = (blk < 2048) ? (const float4*)hs : (const float4*)tk;
    bf16x8* dst = (blk < 2048) ? (bf16x8*)Ahs : (bf16x8*)Ktb;
    int i = (blk & 2047) * 256 + tid;  // units of 8 floats
    float4 v0 = src[2 * i], v1 = src[2 * i + 1];
    bf16x8 o;
    o[0] = (bf16_t)v0.x; o[1] = (bf16_t)v0.y; o[2] = (bf16_t)v0.z; o[3] = (bf16_t)v0.w;
    o[4] = (bf16_t)v1.x; o[5] = (bf16_t)v1.y; o[6] = (bf16_t)v1.z; o[7] = (bf16_t)v1.w;
    dst[i] = o;
  } else {
    __shared__ float tile[32][65];
    const float* in; bf16_t* out; int C, r0, c0; size_t base = 0; bool isV = false;
    if (blk < 5632) {
      int t = blk - 4096; in = Wc; out = WcT; C = 3072;
      r0 = (t / 96) * 64; c0 = (t % 96) * 32;
    } else if (blk < 6144) {
      int t = blk - 5632; in = Wp; out = WpT; C = 1024;
      r0 = (t >> 5) * 64; c0 = (t & 31) * 32;
    } else {
      int t = blk - 6144; int z = t >> 5, rest = t & 31;
      in = tv; out = nullptr; isV = true; C = 64; base = (size_t)z * 65536;
      r0 = (rest >> 1) * 64; c0 = (rest & 1) * 32;
    }
    {
      int rr = tid >> 2, cq = (tid & 3) << 3;
      const float* sp = in + base + (size_t)(r0 + rr) * C + c0 + cq;
      float4 v0 = *(const float4*)sp, v1 = *(const float4*)(sp + 4);
      tile[cq + 0][rr] = v0.x; tile[cq + 1][rr] = v0.y;
      tile[cq + 2][rr] = v0.z; tile[cq + 3][rr] = v0.w;
      tile[cq + 4][rr] = v1.x; tile[cq + 5][rr] = v1.y;
      tile[cq + 6][rr] = v1.z; tile[cq + 7][rr] = v1.w;
    }
    __syncthreads();
    int y = tid >> 3, l = tid & 7;
    if (isV) {
      // key permutation m=b5,b3,b2,b4,b1,b0 (pairs PV chunk quads into 16B)
      f16x8 o;
#pragma unroll
      for (int j = 0; j < 8; j++) {
        int k = ((l & 4) << 3) | ((j & 4) << 2) | ((l & 2) << 2) | ((l & 1) << 2) | (j & 3);
        o[j] = (_Float16)tile[y][k];
      }
      *(f16x8*)(Vtb + base + (size_t)(c0 + y) * 1024 + r0 + (l << 3)) = o;
    } else {
      const float* rowp = &tile[y][l << 3];
      bf16x8 o;
#pragma unroll
      for (int j = 0; j < 8; j++) o[j] = (bf16_t)rowp[j];
      *(bf16x8*)(out + (size_t)(c0 + y) * 1024 + r0 + (l << 3)) = o;
    }
  }
}

// ---------------------------------------------------------------- fused qkv-GEMM + attention
// 256 threads / 4 fat waves. Phase 1: 128x192 GEMM, wave = 64 rows x 96 cols
// (square-ish subtile -> LDS FLOP:byte ~38, balanced vs MFMA). Epilogue writes the
// biased qkv tile to LDS; phase 2 waves each take 32 queries (2 q-groups), sharing
// K/V b128 reads across groups -> half the phase-2 LDS traffic of the 8-wave version.
#define ATTN_M 12.0f
__global__ __launch_bounds__(256, 2) void fused_attn_kernel(
    const bf16_t* __restrict__ Ahs, const bf16_t* __restrict__ WcT,
    const float* __restrict__ bc,
    const bf16_t* __restrict__ Ktxt, const _Float16* __restrict__ VtxtT,
    bf16_t* __restrict__ Aout) {
  const int bh = blockIdx.x;  // 0..63 ; id%8 = bh&7 -> h-locality per XCD
  const int y = blockIdx.y;   // 0..7
  const int qt = (y < 4) ? y : 11 - y;  // co-resident pair (y,y+4) -> constant work/CU
  const int b = bh >> 4, h = bh & 15;
  const int tid = threadIdx.x, wave = tid >> 6, lane = tid & 63;
  const int c = lane & 15, qd = lane >> 4;
  const int m0 = b * 1024 + qt * 128;
  const int i_base2 = qt * 128 + 32 * wave;  // this wave's 32 queries
  const int kt_max = 2 * qt + 1;             // inclusive

  const bf16_t* Ktb = Ktxt + (size_t)bh * 65536;
  const _Float16* Vtb = VtxtT + (size_t)bh * 65536;

  __shared__ __align__(16) char pool[49152];
  bf16_t* Asm = (bf16_t*)pool;             // [0,16K)   phase-1 A staging
  bf16_t* Bsm = (bf16_t*)(pool + 16384);   // [16K,40K) phase-1 B staging
  bf16_t* T = (bf16_t*)pool;               // [0,48K)   qkv tile 128x192 (post-GEMM)
  bf16_t* KsmB = (bf16_t*)pool;            // [0,16K)   phase-2 K dbuf 2x4096 bf16
  _Float16* VsmB = (_Float16*)(pool + 16384);  // [16K,32K) phase-2 V dbuf 2x4096 f16

  // ---------------- phase 1: 128x192 GEMM (q|k|v cols of head h), K=1024, BK=64
  const int wm = (wave & 1) * 64, wn = (wave >> 1) * 96;
  f32x4 acc[4][6];
#pragma unroll
  for (int i = 0; i < 4; i++)
#pragma unroll
    for (int j = 0; j < 6; j++) acc[i][j] = (f32x4){0.f, 0.f, 0.f, 0.f};

  for (int kt = 0; kt < 16; kt++) {
#pragma unroll
    for (int p = 0; p < 4; p++) {
      int chunk = p * 256 + tid;
      int row = chunk >> 3, sb = chunk & 7, kb = sb ^ (row & 7);
      gl_lds16(Ahs + (size_t)(m0 + row) * 1024 + kt * 64 + kb * 8, Asm + chunk * 8);
    }
#pragma unroll
    for (int p = 0; p < 6; p++) {
      int chunk = p * 256 + tid;
      int brow = chunk >> 3, sb = chunk & 7, kb = sb ^ (brow & 7);
      int wrow = (brow >> 6) * 1024 + h * 64 + (brow & 63);
      gl_lds16(WcT + (size_t)wrow * 1024 + kt * 64 + kb * 8, Bsm + chunk * 8);
    }
    __syncthreads();
#pragma unroll
    for (int kk = 0; kk < 2; kk++) {
      bf16x8 af[4], bfr[6];
#pragma unroll
      for (int i = 0; i < 4; i++) {
        int row = wm + 16 * i + c;
        af[i] = *(const bf16x8*)(&Asm[row * 64 + (((4 * kk + qd) ^ (row & 7)) << 3)]);
      }
#pragma unroll
      for (int j = 0; j < 6; j++) {
        int row = wn + 16 * j + c;
        bfr[j] = *(const bf16x8*)(&Bsm[row * 64 + (((4 * kk + qd) ^ (row & 7)) << 3)]);
      }
#pragma unroll
      for (int i = 0; i < 4; i++)
#pragma unroll
        for (int j = 0; j < 6; j++)
          acc[i][j] = __builtin_amdgcn_mfma_f32_16x16x32_bf16(af[i], bfr[j], acc[i][j], 0, 0, 0);
    }
    __syncthreads();
  }

  // ---------------- epilogue: bias + write qkv tile (swizzled row-major, 192 cols)
#pragma unroll
  for (int j = 0; j < 6; j++) {
    int col = wn + 16 * j + c;
    float bv = bc[(col >> 6) * 1024 + h * 64 + (col & 63)];
    int chq = (col >> 3) & 24;  // chunk group base (0,8,16)
    int chl = (col >> 3) & 7;
#pragma unroll
    for (int i = 0; i < 4; i++) {
#pragma unroll
      for (int r = 0; r < 4; r++) {
        int row = wm + 16 * i + 4 * qd + r;
        int ch = chq | (chl ^ (row & 7));
        T[row * 192 + ch * 8 + (col & 7)] = (bf16_t)(acc[i][j][r] + bv);
      }
    }
  }
  __syncthreads();

  // ---------------- extraction: aq frags, self-dot, O init (reads tile)
  bf16x8 aq[2][2];
  float wsc[2];      // wself for query c, per group
  float ws[2][4];    // wself for query 4qd+r, per group
#pragma unroll
  for (int g = 0; g < 2; g++) {
    int row = 32 * wave + 16 * g + c;
    float part = 0.f;
#pragma unroll
    for (int kk = 0; kk < 2; kk++) {
      int ch = (4 * kk + qd) ^ (row & 7);
      aq[g][kk] = *(const bf16x8*)(&T[row * 192 + ch * 8]);
      bf16x8 kf = *(const bf16x8*)(&T[row * 192 + (8 | ch) * 8]);
#pragma unroll
      for (int jj = 0; jj < 8; jj++) part += (float)aq[g][kk][jj] * (float)kf[jj];
    }
    part += __shfl_xor(part, 16, 64);
    part += __shfl_xor(part, 32, 64);
    wsc[g] = __expf(part * 0.125f - ATTN_M);
#pragma unroll
    for (int r = 0; r < 4; r++) ws[g][r] = __shfl(wsc[g], 4 * qd + r, 16);
  }
  f32x4 O[2][4];
#pragma unroll
  for (int g = 0; g < 2; g++) {
#pragma unroll
    for (int u = 0; u < 4; u++) {
#pragma unroll
      for (int r = 0; r < 4; r++) {
        int row = 32 * wave + 16 * g + 4 * qd + r;
        int ch = 16 | ((2 * u + (c >> 3)) ^ (row & 7));
        O[g][u][r] = ws[g][r] * (float)T[row * 192 + ch * 8 + (c & 7)];
      }
    }
  }
  __syncthreads();  // tile dead; safe to reuse pool for K/V staging

  // stage K/V text tile 0
#pragma unroll
  for (int p = 0; p < 2; p++) {
    int chunk = p * 256 + tid;
    int row = chunk >> 3, sb = chunk & 7, kb = sb ^ (row & 7);
    gl_lds16(Ktb + (size_t)row * 64 + kb * 8, KsmB + chunk * 8);
    gl_lds16(Vtb + (size_t)row * 1024 + kb * 8, VsmB + chunk * 8);
  }

  // ---------------- phase 2: flash attention over textual K/V
  float l_loc[2] = {0.f, 0.f};  // textual-l partials for query i_base2+16g+c
  for (int kt = 0; kt <= kt_max; kt++) {
    __syncthreads();
    if (kt < kt_max) {
      int nb = (kt + 1) & 1;
#pragma unroll
      for (int p = 0; p < 2; p++) {
        int chunk = p * 256 + tid;
        int row = chunk >> 3, sb = chunk & 7, kb = sb ^ (row & 7);
        gl_lds16(Ktb + (size_t)((kt + 1) * 64 + row) * 64 + kb * 8,
                 KsmB + nb * 4096 + chunk * 8);
        gl_lds16(Vtb + (size_t)row * 1024 + (kt + 1) * 64 + kb * 8,
                 VsmB + nb * 4096 + chunk * 8);
      }
    }
    // i_base2 % 32 == 0 and 64kt % 32 == 0 -> both groups share one skip condition
    if (64 * kt >= i_base2 + 32) continue;
    const bf16_t* Ks = KsmB + (kt & 1) * 4096;
    const _Float16* Vs = VsmB + (kt & 1) * 4096;

    // S^T = mfma(K, Q): C-frag key = 16t+4qd+r, query = c (per group)
    f32x4 sc[2][4];
#pragma unroll
    for (int t = 0; t < 4; t++) {
      sc[0][t] = (f32x4){0.f, 0.f, 0.f, 0.f};
      sc[1][t] = (f32x4){0.f, 0.f, 0.f, 0.f};
    }
#pragma unroll
    for (int kk = 0; kk < 2; kk++) {
#pragma unroll
      for (int t = 0; t < 4; t++) {
        int row = 16 * t + c;
        bf16x8 bk = *(const bf16x8*)(&Ks[row * 64 + (((4 * kk + qd) ^ (row & 7)) << 3)]);
        sc[0][t] = __builtin_amdgcn_mfma_f32_16x16x32_bf16(bk, aq[0][kk], sc[0][t], 0, 0, 0);
        sc[1][t] = __builtin_amdgcn_mfma_f32_16x16x32_bf16(bk, aq[1][kk], sc[1][t], 0, 0, 0);
      }
    }
    const bool edge = (64 * kt + 63 >= i_base2);
    f16x4 pa[2][4];  // P^T frags == A-operand of 16x16x16 f16 (m=query=c, k=4qd+j)
    if (!edge) {
#pragma unroll
      for (int g = 0; g < 2; g++)
#pragma unroll
        for (int t = 0; t < 4; t++)
#pragma unroll
          for (int r = 0; r < 4; r++) {
            float p = __expf(sc[g][t][r] * 0.125f - ATTN_M);
            l_loc[g] += p;
            pa[g][t][r] = (_Float16)p;
          }
    } else {
#pragma unroll
      for (int g = 0; g < 2; g++)
#pragma unroll
        for (int t = 0; t < 4; t++)
#pragma unroll
          for (int r = 0; r < 4; r++) {
            bool masked = (64 * kt + 16 * t + 4 * qd + r >= i_base2 + 16 * g + c);
            float p = masked ? 0.f : __expf(sc[g][t][r] * 0.125f - ATTN_M);
            l_loc[g] += p;
            pa[g][t][r] = (_Float16)p;
          }
    }
    // PV: V key-permuted so chunk-pair quads sit in one 16B block; shared across groups
#pragma unroll
    for (int tp = 0; tp < 2; tp++) {
#pragma unroll
      for (int u = 0; u < 4; u++) {
        int row = 16 * u + c;
        f16x8 vv = *(const f16x8*)(&Vs[row * 64 + (((4 * tp + qd) ^ (row & 7)) << 3)]);
        f16x4 vlo = __builtin_shufflevector(vv, vv, 0, 1, 2, 3);
        f16x4 vhi = __builtin_shufflevector(vv, vv, 4, 5, 6, 7);
        O[0][u] = __builtin_amdgcn_mfma_f32_16x16x16f16(pa[0][2 * tp], vlo, O[0][u], 0, 0, 0);
        O[0][u] = __builtin_amdgcn_mfma_f32_16x16x16f16(pa[0][2 * tp + 1], vhi, O[0][u], 0, 0, 0);
        O[1][u] = __builtin_amdgcn_mfma_f32_16x16x16f16(pa[1][2 * tp], vlo, O[1][u], 0, 0, 0);
        O[1][u] = __builtin_amdgcn_mfma_f32_16x16x16f16(pa[1][2 * tp + 1], vhi, O[1][u], 0, 0, 0);
      }
    }
  }

  // finalize: reduce l over qd groups, normalize, store
#pragma unroll
  for (int g = 0; g < 2; g++) {
    float l = l_loc[g];
    l += __shfl_xor(l, 16, 64);
    l += __shfl_xor(l, 32, 64);
#pragma unroll
    for (int r = 0; r < 4; r++) {
      float lq = __shfl(l, 4 * qd + r, 16);
      float inv = 1.0f / (lq + ws[g][r]);
      int i = i_base2 + 16 * g + 4 * qd + r;
#pragma unroll
      for (int u = 0; u < 4; u++)
        Aout[((size_t)b * 1024 + i) * 1024 + h * 64 + 16 * u + c] = (bf16_t)(O[g][u][r] * inv);
    }
  }
}

// ---------------------------------------------------------------- GEMM 2: out = Aout @ Wp + bp
// 64x128 tile -> 512 blocks (2/CU, 16 waves/CU) + explicit LDS double-buffer.
__global__ __launch_bounds__(256) void gemm_out_kernel(
    const bf16_t* __restrict__ A, const bf16_t* __restrict__ Bt, const float* __restrict__ bias,
    float* __restrict__ out) {
  __shared__ bf16_t Asm[2][4096];
  __shared__ bf16_t Bsm[2][8192];
  const int tid = threadIdx.x;
  const int wave = tid >> 6, lane = tid & 63;
  const int c = lane & 15, qd = lane >> 4;
  const int wn = wave * 32;
  const int m0 = blockIdx.y * 64, n0 = blockIdx.x * 128;

  f32x4 acc[4][2];
#pragma unroll
  for (int i = 0; i < 4; i++)
#pragma unroll
    for (int j = 0; j < 2; j++) acc[i][j] = (f32x4){0.f, 0.f, 0.f, 0.f};

#pragma unroll
  for (int p = 0; p < 2; p++) {
    int chunk = p * 256 + tid;
    int row = chunk >> 3, sb = chunk & 7, kb = sb ^ (row & 7);
    gl_lds16(A + (size_t)(m0 + row) * 1024 + kb * 8, &Asm[0][chunk * 8]);
  }
#pragma unroll
  for (int p = 0; p < 4; p++) {
    int chunk = p * 256 + tid;
    int row = chunk >> 3, sb = chunk & 7, kb = sb ^ (row & 7);
    gl_lds16(Bt + (size_t)(n0 + row) * 1024 + kb * 8, &Bsm[0][chunk * 8]);
  }
  for (int it = 0; it < 16; it++) {
    __syncthreads();
    if (it < 15) {
      int nbuf = (it + 1) & 1, kt = (it + 1) * 64;
#pragma unroll
      for (int p = 0; p < 2; p++) {
        int chunk = p * 256 + tid;
        int row = chunk >> 3, sb = chunk & 7, kb = sb ^ (row & 7);
        gl_lds16(A + (size_t)(m0 + row) * 1024 + kt + kb * 8, &Asm[nbuf][chunk * 8]);
      }
#pragma unroll
      for (int p = 0; p < 4; p++) {
        int chunk = p * 256 + tid;
        int row = chunk >> 3, sb = chunk & 7, kb = sb ^ (row & 7);
        gl_lds16(Bt + (size_t)(n0 + row) * 1024 + kt + kb * 8, &Bsm[nbuf][chunk * 8]);
      }
    }
    const int bs = it & 1;
#pragma unroll
    for (int kk = 0; kk < 2; kk++) {
      bf16x8 af[4], bfr[2];
#pragma unroll
      for (int i = 0; i < 4; i++) {
        int row = 16 * i + c;
        af[i] = *(const bf16x8*)(&Asm[bs][row * 64 + (((4 * kk + qd) ^ (row & 7)) << 3)]);
      }
#pragma unroll
      for (int j = 0; j < 2; j++) {
        int row = wn + 16 * j + c;
        bfr[j] = *(const bf16x8*)(&Bsm[bs][row * 64 + (((4 * kk + qd) ^ (row & 7)) << 3)]);
      }
#pragma unroll
      for (int i = 0; i < 4; i++)
#pragma unroll
        for (int j = 0; j < 2; j++)
          acc[i][j] = __builtin_amdgcn_mfma_f32_16x16x32_bf16(af[i], bfr[j], acc[i][j], 0, 0, 0);
    }
  }
#pragma unroll
  for (int j = 0; j < 2; j++) {
    int n = n0 + wn + 16 * j + c;
    float bv = bias[n];
#pragma unroll
    for (int i = 0; i < 4; i++) {
#pragma unroll
      for (int r = 0; r < 4; r++) {
        int m = m0 + 16 * i + 4 * qd + r;
        out[(size_t)m * 1024 + n] = acc[i][j][r] + bv;
      }
    }
  }
}

// ----------------------------------------------------------------
extern "C" void kernel_launch(void* const* d_in, const int* in_sizes, int n_in,
                              void* d_out, int out_size, void* d_ws, size_t ws_size,
                              hipStream_t stream) {
  const float* hs = (const float*)d_in[0];
  const float* tk = (const float*)d_in[1];
  const float* tv = (const float*)d_in[2];
  const float* Wc = (const float*)d_in[3];
  const float* bc = (const float*)d_in[4];
  const float* Wp = (const float*)d_in[5];
  const float* bp = (const float*)d_in[6];
  float* out = (float*)d_out;

  bf16_t* ws = (bf16_t*)d_ws;
  const size_t M1 = 1u << 20;
  bf16_t* Ahs  = ws;                          // hs bf16 (4096 x 1024)
  bf16_t* WcT  = ws + 4 * M1;                 // Wc^T (3072 x 1024)
  bf16_t* WpT  = ws + 7 * M1;                 // Wp^T (1024 x 1024)
  bf16_t* Ktb  = ws + 8 * M1;                 // textual_key bf16 (B,H,S,HD)
  _Float16* Vtb = (_Float16*)(ws + 12 * M1);  // textual_value^T fp16, key-permuted
  bf16_t* Aout = ws + 28 * M1;                // attention out, (B*S, D) bf16

  prep_kernel<<<8192, 256, 0, stream>>>(hs, tk, tv, Wc, Wp, Ahs, Ktb, Vtb, WcT, WpT);
  fused_attn_kernel<<<dim3(64, 8), 256, 0, stream>>>(Ahs, WcT, bc, Ktb, Vtb, Aout);
  gemm_out_kernel<<<dim3(8, 64), 256, 0, stream>>>(Aout, WpT, bp, out);
}